// Round 2
// baseline (53615.771 us; speedup 1.0000x reference)
//
#include <hip/hip_runtime.h>
#include <hip/hip_bf16.h>

// ---------------- problem constants ----------------
constexpr int N_   = 32;
constexpr int C_   = 3;
constexpr int P_   = 14;      // patches per side
constexpr int PHW  = 16;      // patch height/width
constexpr int IND  = 768;     // C*16*16
constexpr int D_   = 768;
constexpr int NH_  = 12;
constexpr int DH_  = 64;
constexpr int L_   = 12;
constexpr int OUT_ = 1000;
constexpr int S_   = 197;     // tokens
constexpr int MLP_ = 3072;
constexpr int NPATCH = P_ * P_;      // 196
constexpr int ROWS   = N_ * S_;      // 6304
constexpr int TROWS  = N_ * NPATCH;  // 6272

// ---------------- generic tiled batched GEMM ----------------
// C = alpha * A@B (+bias) (+act) (+= C if accum), with batch offsets.
// A: [M,K] row-major (lda). B: [K,N] row-major (ldb) or, if TRANSB,
// stored as Bt[N,K] row-major (ldb = stride between n-rows).
// batch index bz -> bi = bz / batchInner, bj = bz % batchInner;
// each pointer gets  + bi*off?1 + bj*off?2.
template<int BM, int BN, int BK, int TM, int TN, bool TRANSB>
__global__ __launch_bounds__((BM / TM) * (BN / TN))
void gemm_kernel(const float* __restrict__ Ag,
                 const float* __restrict__ Bg,
                 float* __restrict__ Cg,
                 const float* __restrict__ biasg,
                 int M, int N, int K,
                 int lda, int ldb, int ldc,
                 long offA1, long offA2,
                 long offB1, long offB2,
                 long offC1, long offC2,
                 long offS1, long offS2,
                 int batchInner,
                 float alpha, int act, int accum)
{
    constexpr int THREADS = (BM / TM) * (BN / TN);
    const int bz = blockIdx.z;
    const int bi = bz / batchInner;
    const int bj = bz % batchInner;
    const float* A = Ag + bi * offA1 + bj * offA2;
    const float* B = Bg + bi * offB1 + bj * offB2;
    float* C = Cg + bi * offC1 + bj * offC2;
    const float* bias = biasg ? (biasg + bi * offS1 + bj * offS2) : nullptr;

    __shared__ __align__(16) float As[BK][BM + 4];
    __shared__ __align__(16) float Bs[BK][BN + 4];

    const int tid  = threadIdx.x;
    const int row0 = blockIdx.y * BM;
    const int col0 = blockIdx.x * BN;
    const int tr = tid / (BN / TN);
    const int tc = tid % (BN / TN);

    float acc[TM][TN];
#pragma unroll
    for (int i = 0; i < TM; ++i)
#pragma unroll
        for (int j = 0; j < TN; ++j) acc[i][j] = 0.f;

    for (int k0 = 0; k0 < K; k0 += BK) {
        // ---- stage A tile (BM x BK) into As[k][m] ----
#pragma unroll
        for (int it = 0; it < (BM * BK) / THREADS; ++it) {
            int idx = it * THREADS + tid;
            int m  = idx / BK;
            int kk = idx % BK;
            int gr = row0 + m, gk = k0 + kk;
            float v = 0.f;
            if (gr < M && gk < K) v = A[(long)gr * lda + gk];
            As[kk][m] = v;
        }
        // ---- stage B tile (BK x BN) into Bs[k][n] ----
#pragma unroll
        for (int it = 0; it < (BK * BN) / THREADS; ++it) {
            int idx = it * THREADS + tid;
            if constexpr (!TRANSB) {
                int kk = idx / BN;
                int nn = idx % BN;
                int gk = k0 + kk, gn = col0 + nn;
                float v = 0.f;
                if (gk < K && gn < N) v = B[(long)gk * ldb + gn];
                Bs[kk][nn] = v;
            } else {
                int nn = idx / BK;
                int kk = idx % BK;
                int gk = k0 + kk, gn = col0 + nn;
                float v = 0.f;
                if (gk < K && gn < N) v = B[(long)gn * ldb + gk];
                Bs[kk][nn] = v;
            }
        }
        __syncthreads();
        // ---- compute ----
#pragma unroll
        for (int kk = 0; kk < BK; ++kk) {
            float a[TM], b[TN];
#pragma unroll
            for (int i = 0; i < TM; ++i) a[i] = As[kk][tr * TM + i];
#pragma unroll
            for (int j = 0; j < TN; ++j) b[j] = Bs[kk][tc * TN + j];
#pragma unroll
            for (int i = 0; i < TM; ++i)
#pragma unroll
                for (int j = 0; j < TN; ++j)
                    acc[i][j] = fmaf(a[i], b[j], acc[i][j]);
        }
        __syncthreads();
    }

    // ---- epilogue ----
#pragma unroll
    for (int i = 0; i < TM; ++i) {
        int gr = row0 + tr * TM + i;
        if (gr >= M) continue;
#pragma unroll
        for (int j = 0; j < TN; ++j) {
            int gn = col0 + tc * TN + j;
            if (gn >= N) continue;
            float v = acc[i][j] * alpha;
            if (bias) v += bias[gn];
            if (act == 1) v = 0.5f * v * (1.f + erff(v * 0.70710678118654752f));
            long ci = (long)gr * ldc + gn;
            if (accum) v += C[ci];
            C[ci] = v;
        }
    }
}

// ---------------- im2col (patchify) ----------------
__global__ __launch_bounds__(256)
void im2col_kernel(const float* __restrict__ img, float* __restrict__ patches)
{
    long idx = (long)blockIdx.x * 256 + threadIdx.x;
    if (idx >= (long)TROWS * IND) return;
    int e = (int)(idx % IND);                // c*256 + ph*16 + pw
    int t = (int)((idx / IND) % NPATCH);     // py*14 + px
    int n = (int)(idx / ((long)IND * NPATCH));
    int pw = e & 15;
    int ph = (e >> 4) & 15;
    int c  = e >> 8;
    int px = t % P_;
    int py = t / P_;
    patches[idx] = img[(((long)n * C_ + c) * 224 + py * PHW + ph) * 224 + px * PHW + pw];
}

// ---------------- assemble x = [cls ; tokens] + pos ----------------
__global__ __launch_bounds__(256)
void assemble_kernel(const float* __restrict__ tokens,
                     const float* __restrict__ cls,
                     const float* __restrict__ pos,
                     float* __restrict__ x)
{
    long idx = (long)blockIdx.x * 256 + threadIdx.x;
    if (idx >= (long)ROWS * D_) return;
    int d = (int)(idx % D_);
    int s = (int)((idx / D_) % S_);
    long n = idx / ((long)D_ * S_);
    float v = (s == 0) ? cls[d] : tokens[((long)n * NPATCH + (s - 1)) * D_ + d];
    x[idx] = v + pos[(long)s * D_ + d];
}

// ---------------- layernorm (row = 768) ----------------
__global__ __launch_bounds__(256)
void layernorm_kernel(const float* __restrict__ x, float* __restrict__ out,
                      const float* __restrict__ g, const float* __restrict__ b)
{
    long row = blockIdx.x;
    const float* xr = x + row * D_;
    float* orow = out + row * D_;
    int tid = threadIdx.x;
    float v0 = xr[tid], v1 = xr[tid + 256], v2 = xr[tid + 512];
    float s  = v0 + v1 + v2;
    float sq = v0 * v0 + v1 * v1 + v2 * v2;
    for (int off = 32; off > 0; off >>= 1) {
        s  += __shfl_down(s, off);
        sq += __shfl_down(sq, off);
    }
    __shared__ float rs[4], rq[4];
    int wave = tid >> 6, lane = tid & 63;
    if (lane == 0) { rs[wave] = s; rq[wave] = sq; }
    __syncthreads();
    float S  = rs[0] + rs[1] + rs[2] + rs[3];
    float SQ = rq[0] + rq[1] + rq[2] + rq[3];
    float mean = S * (1.f / 768.f);
    float var  = SQ * (1.f / 768.f) - mean * mean;
    float rstd = rsqrtf(var + 1e-5f);
    orow[tid]       = (v0 - mean) * rstd * g[tid]       + b[tid];
    orow[tid + 256] = (v1 - mean) * rstd * g[tid + 256] + b[tid + 256];
    orow[tid + 512] = (v2 - mean) * rstd * g[tid + 512] + b[tid + 512];
}

// ---------------- softmax over 197 (one wave per row) ----------------
__global__ __launch_bounds__(64)
void softmax197_kernel(float* __restrict__ scores)
{
    long row = blockIdx.x;
    float* p = scores + row * S_;
    int lane = threadIdx.x;
    float v[4];
    float mx = -INFINITY;
#pragma unroll
    for (int i = 0; i < 4; ++i) {
        int idx = lane + i * 64;
        v[i] = (idx < S_) ? p[idx] : -INFINITY;
        mx = fmaxf(mx, v[i]);
    }
    for (int off = 32; off > 0; off >>= 1) mx = fmaxf(mx, __shfl_xor(mx, off));
    float sum = 0.f;
#pragma unroll
    for (int i = 0; i < 4; ++i) {
        int idx = lane + i * 64;
        if (idx < S_) { v[i] = expf(v[i] - mx); sum += v[i]; }
    }
    for (int off = 32; off > 0; off >>= 1) sum += __shfl_xor(sum, off);
    float inv = 1.f / sum;
#pragma unroll
    for (int i = 0; i < 4; ++i) {
        int idx = lane + i * 64;
        if (idx < S_) p[idx] = v[i] * inv;
    }
}

// ---------------- final softmax over 1000 ----------------
__global__ __launch_bounds__(256)
void softmax_out_kernel(const float* __restrict__ logits, float* __restrict__ out)
{
    int row = blockIdx.x;
    int tid = threadIdx.x;
    const float* p = logits + (long)row * OUT_;
    float v[4];
    float mx = -INFINITY;
#pragma unroll
    for (int i = 0; i < 4; ++i) {
        int idx = tid + i * 256;
        v[i] = (idx < OUT_) ? p[idx] : -INFINITY;
        mx = fmaxf(mx, v[i]);
    }
    int wave = tid >> 6, lane = tid & 63;
    for (int off = 32; off > 0; off >>= 1) mx = fmaxf(mx, __shfl_xor(mx, off));
    __shared__ float r1[4], r2[4];
    if (lane == 0) r1[wave] = mx;
    __syncthreads();
    mx = fmaxf(fmaxf(r1[0], r1[1]), fmaxf(r1[2], r1[3]));
    float sum = 0.f;
#pragma unroll
    for (int i = 0; i < 4; ++i) {
        int idx = tid + i * 256;
        if (idx < OUT_) { v[i] = expf(v[i] - mx); sum += v[i]; }
    }
    for (int off = 32; off > 0; off >>= 1) sum += __shfl_xor(sum, off);
    if (lane == 0) r2[wave] = sum;
    __syncthreads();
    sum = r2[0] + r2[1] + r2[2] + r2[3];
    float inv = 1.f / sum;
#pragma unroll
    for (int i = 0; i < 4; ++i) {
        int idx = tid + i * 256;
        if (idx < OUT_) out[(long)row * OUT_ + idx] = v[i] * inv;
    }
}

// ---------------- host driver ----------------
extern "C" void kernel_launch(void* const* d_in, const int* in_sizes, int n_in,
                              void* d_out, int out_size, void* d_ws, size_t ws_size,
                              hipStream_t stream)
{
    const float* images = (const float*)d_in[0];
    const float* W_map  = (const float*)d_in[1];
    const float* b_map  = (const float*)d_in[2];
    const float* cls    = (const float*)d_in[3];
    const float* pos    = (const float*)d_in[4];
    const float* ln1_g  = (const float*)d_in[5];
    const float* ln1_b  = (const float*)d_in[6];
    const float* Wq     = (const float*)d_in[7];
    const float* bq     = (const float*)d_in[8];
    const float* Wk     = (const float*)d_in[9];
    const float* bk     = (const float*)d_in[10];
    const float* Wv     = (const float*)d_in[11];
    const float* bv     = (const float*)d_in[12];
    const float* ln2_g  = (const float*)d_in[13];
    const float* ln2_b  = (const float*)d_in[14];
    const float* W1     = (const float*)d_in[15];
    const float* b1     = (const float*)d_in[16];
    const float* W2     = (const float*)d_in[17];
    const float* b2     = (const float*)d_in[18];
    const float* W_head = (const float*)d_in[19];
    const float* b_head = (const float*)d_in[20];

    float* ws = (float*)d_ws;
    const long XSZ = (long)ROWS * D_;  // 4,841,472 floats
    float* x   = ws;
    float* hbf = x + XSZ;
    float* qb  = hbf + XSZ;
    float* kb  = qb + XSZ;
    float* vb  = kb + XSZ;
    float* un  = vb + XSZ;             // union region (re-used across phases)
    float* patches = un;                         // 6272*768
    float* tokens  = un + (long)TROWS * IND;     // 6272*768
    float* scores  = un;                         // 384*197*197
    float* mbuf    = un;                         // 6304*3072
    float* logits  = un;                         // 32*1000 (after loop)

    // ---- patch embedding ----
    {
        long tot = (long)TROWS * IND;
        im2col_kernel<<<(int)((tot + 255) / 256), 256, 0, stream>>>(images, patches);
    }
    {
        dim3 g((D_ + 127) / 128, (TROWS + 127) / 128, 1);
        hipLaunchKernelGGL((gemm_kernel<128, 128, 32, 8, 8, false>), g, dim3(256), 0, stream,
                           patches, W_map, tokens, b_map,
                           TROWS, D_, IND, IND, D_, D_,
                           0L, 0L, 0L, 0L, 0L, 0L, 0L, 0L, 1, 1.f, 0, 0);
    }
    {
        long tot = (long)ROWS * D_;
        assemble_kernel<<<(int)((tot + 255) / 256), 256, 0, stream>>>(tokens, cls, pos, x);
    }

    for (int l = 0; l < L_; ++l) {
        layernorm_kernel<<<ROWS, 256, 0, stream>>>(x, hbf, ln1_g + (long)l * D_, ln1_b + (long)l * D_);

        // per-head QKV projections: batched GEMM over heads
        const float* Wqkv[3] = {Wq + (long)l * NH_ * DH_ * DH_,
                                Wk + (long)l * NH_ * DH_ * DH_,
                                Wv + (long)l * NH_ * DH_ * DH_};
        const float* bqkv[3] = {bq + (long)l * NH_ * DH_,
                                bk + (long)l * NH_ * DH_,
                                bv + (long)l * NH_ * DH_};
        float* oqkv[3] = {qb, kb, vb};
        for (int i = 0; i < 3; ++i) {
            dim3 g(1, (ROWS + 63) / 64, NH_);
            hipLaunchKernelGGL((gemm_kernel<64, 64, 16, 4, 4, false>), g, dim3(256), 0, stream,
                               hbf, Wqkv[i], oqkv[i], bqkv[i],
                               ROWS, DH_, DH_, D_, DH_, D_,
                               0L, 64L, 0L, (long)DH_ * DH_, 0L, 64L, 0L, 64L,
                               NH_, 1.f, 0, 0);
        }

        // scores = q @ k^T / 8   [per (n,h): 197x197, K=64]
        {
            dim3 g((S_ + 63) / 64, (S_ + 63) / 64, N_ * NH_);
            hipLaunchKernelGGL((gemm_kernel<64, 64, 16, 4, 4, true>), g, dim3(256), 0, stream,
                               qb, kb, scores, (const float*)nullptr,
                               S_, S_, DH_, D_, D_, S_,
                               (long)S_ * D_, 64L, (long)S_ * D_, 64L,
                               (long)NH_ * S_ * S_, (long)S_ * S_, 0L, 0L,
                               NH_, 0.125f, 0, 0);
        }
        softmax197_kernel<<<N_ * NH_ * S_, 64, 0, stream>>>(scores);

        // x += attn @ v   [per (n,h): 197x64, K=197] (heads write disjoint cols)
        {
            dim3 g(1, (S_ + 63) / 64, N_ * NH_);
            hipLaunchKernelGGL((gemm_kernel<64, 64, 16, 4, 4, false>), g, dim3(256), 0, stream,
                               scores, vb, x, (const float*)nullptr,
                               S_, DH_, S_, S_, D_, D_,
                               (long)NH_ * S_ * S_, (long)S_ * S_,
                               (long)S_ * D_, 64L, (long)S_ * D_, 64L, 0L, 0L,
                               NH_, 1.f, 0, 1);
        }

        layernorm_kernel<<<ROWS, 256, 0, stream>>>(x, hbf, ln2_g + (long)l * D_, ln2_b + (long)l * D_);

        // MLP1: m = gelu(h @ W1 + b1)
        {
            dim3 g((MLP_ + 127) / 128, (ROWS + 127) / 128, 1);
            hipLaunchKernelGGL((gemm_kernel<128, 128, 32, 8, 8, false>), g, dim3(256), 0, stream,
                               hbf, W1 + (long)l * D_ * MLP_, mbuf, b1 + (long)l * MLP_,
                               ROWS, MLP_, D_, D_, MLP_, MLP_,
                               0L, 0L, 0L, 0L, 0L, 0L, 0L, 0L, 1, 1.f, 1, 0);
        }
        // MLP2: x += m @ W2 + b2
        {
            dim3 g((D_ + 127) / 128, (ROWS + 127) / 128, 1);
            hipLaunchKernelGGL((gemm_kernel<128, 128, 32, 8, 8, false>), g, dim3(256), 0, stream,
                               mbuf, W2 + (long)l * MLP_ * D_, x, b2 + (long)l * D_,
                               ROWS, D_, MLP_, MLP_, D_, D_,
                               0L, 0L, 0L, 0L, 0L, 0L, 0L, 0L, 1, 1.f, 0, 1);
        }
    }

    // head: logits = x[:,0,:] @ W_head + b_head
    {
        dim3 g((OUT_ + 63) / 64, 1, 1);
        hipLaunchKernelGGL((gemm_kernel<64, 64, 16, 4, 4, false>), g, dim3(256), 0, stream,
                           x, W_head, logits, b_head,
                           N_, OUT_, D_, S_ * D_, OUT_, OUT_,
                           0L, 0L, 0L, 0L, 0L, 0L, 0L, 0L, 1, 1.f, 0, 0);
    }
    softmax_out_kernel<<<N_, 256, 0, stream>>>(logits, (float*)d_out);
}

// Round 3
// 5027.995 us; speedup vs baseline: 10.6635x; 10.6635x over previous
//
#include <hip/hip_runtime.h>
#include <hip/hip_bf16.h>

// ---------------- problem constants ----------------
constexpr int N_   = 32;
constexpr int C_   = 3;
constexpr int P_   = 14;
constexpr int PHW  = 16;
constexpr int IND  = 768;
constexpr int D_   = 768;
constexpr int NH_  = 12;
constexpr int DH_  = 64;
constexpr int L_   = 12;
constexpr int OUT_ = 1000;
constexpr int S_   = 197;
constexpr int MLP_ = 3072;
constexpr int NPATCH = P_ * P_;      // 196
constexpr int ROWS   = N_ * S_;      // 6304
constexpr int TROWS  = N_ * NPATCH;  // 6272
constexpr int RPAD   = 6400;         // rows padded to 128-multiple
constexpr int SP_R   = 256;          // scores rows pad (2 m-tiles)
constexpr int SP_C   = 224;          // scores cols pad (K-multiple of 32)

typedef __attribute__((ext_vector_type(8))) short bf16x8;
typedef __attribute__((ext_vector_type(4))) float f32x4;

__device__ __forceinline__ float bf2f(ushort u) {
    union { float f; unsigned int i; } v; v.i = ((unsigned int)u) << 16; return v.f;
}
__device__ __forceinline__ ushort f2bf(float f) {
    union { float f; unsigned int i; } v; v.f = f;
    unsigned int r = v.i + 0x7fffu + ((v.i >> 16) & 1u);
    return (ushort)(r >> 16);
}

// =================================================================
// bf16 MFMA GEMM (m97-style): C = alpha*A@Bt^T (+bias)(+gelu)(+=C)
// A [M,K] bf16 row-major, Bt [N,K] bf16 row-major.
// 128x128 tile, BK=32, 4 waves, each wave 64x64 via 4x4 16x16x32 MFMA.
// batch z: bi=z/inner, bj=z%inner; ptr += bi*off?1 + bj*off?2.
// =================================================================
__global__ __launch_bounds__(256)
void mfma_gemm(const ushort* __restrict__ Ag,
               const ushort* __restrict__ Bg,
               void* __restrict__ Cg,
               const float* __restrict__ bias,
               int M, int N, int K,
               int lda, int ldb, int ldc,
               long offA1, long offA2,
               long offB1, long offB2,
               long offC1, long offC2,
               int inner, float alpha, int act, int outbf, int accum)
{
    const int bz = blockIdx.z;
    const int bi = bz / inner, bj = bz % inner;
    const ushort* A = Ag + bi * offA1 + bj * offA2;
    const ushort* B = Bg + bi * offB1 + bj * offB2;
    const long coff = bi * offC1 + bj * offC2;

    __shared__ ushort As[128 * 32];
    __shared__ ushort Bs[128 * 32];

    const int tid  = threadIdx.x;
    const int w    = tid >> 6;
    const int lhi  = (tid & 63) >> 4;
    const int llo  = tid & 15;
    const int wr   = w >> 1, wc = w & 1;
    const int row0 = blockIdx.y * 128;
    const int col0 = blockIdx.x * 128;

    f32x4 acc[4][4];
#pragma unroll
    for (int m = 0; m < 4; ++m)
#pragma unroll
        for (int n = 0; n < 4; ++n) acc[m][n] = (f32x4){0.f, 0.f, 0.f, 0.f};

    // staging chunk indices (16B chunks): cidx = it*256+tid, row=cidx>>2, slot=cidx&3
    // LDS holds global chunk (row, slot ^ f(row)) at physical (row, slot), f(r)=(r>>1)&3
    int r0s = (0 * 256 + tid) >> 2, s0s = tid & 3;
    int r1s = (1 * 256 + tid) >> 2, s1s = tid & 3;
    int ss0 = s0s ^ ((r0s >> 1) & 3);
    int ss1 = s1s ^ ((r1s >> 1) & 3);
    ushort* dstA0 = As + ((0 * 256 + (w << 6)) << 3);
    ushort* dstA1 = As + ((1 * 256 + (w << 6)) << 3);
    ushort* dstB0 = Bs + ((0 * 256 + (w << 6)) << 3);
    ushort* dstB1 = Bs + ((1 * 256 + (w << 6)) << 3);

    for (int k0 = 0; k0 < K; k0 += 32) {
        const ushort* a0 = A + (long)(row0 + r0s) * lda + k0 + ss0 * 8;
        const ushort* a1 = A + (long)(row0 + r1s) * lda + k0 + ss1 * 8;
        const ushort* b0 = B + (long)(col0 + r0s) * ldb + k0 + ss0 * 8;
        const ushort* b1 = B + (long)(col0 + r1s) * ldb + k0 + ss1 * 8;
        __builtin_amdgcn_global_load_lds((const __attribute__((address_space(1))) void*)a0,
                                         (__attribute__((address_space(3))) void*)dstA0, 16, 0, 0);
        __builtin_amdgcn_global_load_lds((const __attribute__((address_space(1))) void*)a1,
                                         (__attribute__((address_space(3))) void*)dstA1, 16, 0, 0);
        __builtin_amdgcn_global_load_lds((const __attribute__((address_space(1))) void*)b0,
                                         (__attribute__((address_space(3))) void*)dstB0, 16, 0, 0);
        __builtin_amdgcn_global_load_lds((const __attribute__((address_space(1))) void*)b1,
                                         (__attribute__((address_space(3))) void*)dstB1, 16, 0, 0);
        __syncthreads();

        bf16x8 av[4], bv[4];
#pragma unroll
        for (int m = 0; m < 4; ++m) {
            int R = wr * 64 + m * 16 + llo;
            av[m] = *(const bf16x8*)(As + R * 32 + ((lhi ^ ((R >> 1) & 3)) << 3));
        }
#pragma unroll
        for (int n = 0; n < 4; ++n) {
            int R = wc * 64 + n * 16 + llo;
            bv[n] = *(const bf16x8*)(Bs + R * 32 + ((lhi ^ ((R >> 1) & 3)) << 3));
        }
#pragma unroll
        for (int m = 0; m < 4; ++m)
#pragma unroll
            for (int n = 0; n < 4; ++n)
                acc[m][n] = __builtin_amdgcn_mfma_f32_16x16x32_bf16(av[m], bv[n], acc[m][n], 0, 0, 0);
        __syncthreads();
    }

    // epilogue: C[row,col], row=(lane>>4)*4+reg, col=lane&15 within 16x16 frag
    float* Cf = (float*)Cg + coff;
    ushort* Ch = (ushort*)Cg + coff;
#pragma unroll
    for (int m = 0; m < 4; ++m) {
#pragma unroll
        for (int n = 0; n < 4; ++n) {
#pragma unroll
            for (int j = 0; j < 4; ++j) {
                int gr = row0 + wr * 64 + m * 16 + lhi * 4 + j;
                int gc = col0 + wc * 64 + n * 16 + llo;
                if (gr < M && gc < N) {
                    float v = acc[m][n][j] * alpha;
                    if (bias) v += bias[gc];
                    if (act == 1) v = 0.5f * v * (1.f + erff(v * 0.70710678118654752f));
                    long ci = (long)gr * ldc + gc;
                    if (outbf) {
                        Ch[ci] = f2bf(v);
                    } else {
                        if (accum) v += Cf[ci];
                        Cf[ci] = v;
                    }
                }
            }
        }
    }
}

// ---------------- im2col (patchify) -> bf16 ----------------
__global__ __launch_bounds__(256)
void im2col_kernel(const float* __restrict__ img, ushort* __restrict__ patches)
{
    long idx = (long)blockIdx.x * 256 + threadIdx.x;
    if (idx >= (long)TROWS * IND) return;
    int e = (int)(idx % IND);
    int t = (int)((idx / IND) % NPATCH);
    int n = (int)(idx / ((long)IND * NPATCH));
    int pw = e & 15, ph = (e >> 4) & 15, c = e >> 8;
    int px = t % P_, py = t / P_;
    patches[idx] = f2bf(img[(((long)n * C_ + c) * 224 + py * PHW + ph) * 224 + px * PHW + pw]);
}

// ---------------- assemble x = [cls ; tokens] + pos (fp32) ----------------
__global__ __launch_bounds__(256)
void assemble_kernel(const float* __restrict__ tokens,
                     const float* __restrict__ cls,
                     const float* __restrict__ pos,
                     float* __restrict__ x)
{
    long idx = (long)blockIdx.x * 256 + threadIdx.x;
    if (idx >= (long)ROWS * D_) return;
    int d = (int)(idx % D_);
    int s = (int)((idx / D_) % S_);
    long n = idx / ((long)D_ * S_);
    float v = (s == 0) ? cls[d] : tokens[((long)n * NPATCH + (s - 1)) * D_ + d];
    x[idx] = v + pos[(long)s * D_ + d];
}

// ---------------- layernorm fp32 -> bf16 ----------------
__global__ __launch_bounds__(256)
void layernorm_kernel(const float* __restrict__ x, ushort* __restrict__ out,
                      const float* __restrict__ g, const float* __restrict__ b)
{
    long row = blockIdx.x;
    const float* xr = x + row * D_;
    ushort* orow = out + row * D_;
    int tid = threadIdx.x;
    float v0 = xr[tid], v1 = xr[tid + 256], v2 = xr[tid + 512];
    float s  = v0 + v1 + v2;
    float sq = v0 * v0 + v1 * v1 + v2 * v2;
    for (int off = 32; off > 0; off >>= 1) {
        s  += __shfl_down(s, off);
        sq += __shfl_down(sq, off);
    }
    __shared__ float rs[4], rq[4];
    int wave = tid >> 6, lane = tid & 63;
    if (lane == 0) { rs[wave] = s; rq[wave] = sq; }
    __syncthreads();
    float S  = rs[0] + rs[1] + rs[2] + rs[3];
    float SQ = rq[0] + rq[1] + rq[2] + rq[3];
    float mean = S * (1.f / 768.f);
    float var  = SQ * (1.f / 768.f) - mean * mean;
    float rstd = rsqrtf(var + 1e-5f);
    orow[tid]       = f2bf((v0 - mean) * rstd * g[tid]       + b[tid]);
    orow[tid + 256] = f2bf((v1 - mean) * rstd * g[tid + 256] + b[tid + 256]);
    orow[tid + 512] = f2bf((v2 - mean) * rstd * g[tid + 512] + b[tid + 512]);
}

// ---------------- softmax over 197, bf16 in-place, zero-pad to 224 ----------------
__global__ __launch_bounds__(64)
void softmax197_kernel(ushort* __restrict__ scores)
{
    long bid = blockIdx.x;
    long batch = bid / S_;
    long r = bid % S_;
    ushort* p = scores + (batch * SP_R + r) * SP_C;
    int lane = threadIdx.x;
    float v[4];
    float mx = -INFINITY;
#pragma unroll
    for (int i = 0; i < 4; ++i) {
        int idx = lane + i * 64;
        v[i] = (idx < S_) ? bf2f(p[idx]) : -INFINITY;
        mx = fmaxf(mx, v[i]);
    }
    for (int off = 32; off > 0; off >>= 1) mx = fmaxf(mx, __shfl_xor(mx, off));
    float sum = 0.f;
#pragma unroll
    for (int i = 0; i < 4; ++i) {
        int idx = lane + i * 64;
        if (idx < S_) { v[i] = expf(v[i] - mx); sum += v[i]; }
    }
    for (int off = 32; off > 0; off >>= 1) sum += __shfl_xor(sum, off);
    float inv = 1.f / sum;
#pragma unroll
    for (int i = 0; i < 4; ++i) {
        int idx = lane + i * 64;
        if (idx < SP_C) p[idx] = (idx < S_) ? f2bf(v[i] * inv) : (ushort)0;
    }
}

// ---------------- V transpose: qkv V-section -> Vt [batch][64][224] (zero-padded) ----------------
__global__ __launch_bounds__(256)
void vtrans_kernel(const ushort* __restrict__ qkv, ushort* __restrict__ Vt)
{
    int b = blockIdx.z;
    int n = b / NH_, h = b % NH_;
    __shared__ ushort t[32][33];
    int s0 = blockIdx.x * 32, d0 = blockIdx.y * 32;
    int tx = threadIdx.x & 31, ty = threadIdx.x >> 5;
#pragma unroll
    for (int i = 0; i < 4; ++i) {
        int s = s0 + ty * 4 + i;
        ushort v = 0;
        if (s < S_) v = qkv[(long)(n * S_ + s) * 2304 + 1536 + h * 64 + d0 + tx];
        t[ty * 4 + i][tx] = v;
    }
    __syncthreads();
#pragma unroll
    for (int i = 0; i < 4; ++i) {
        int dh = d0 + ty * 4 + i;
        int s  = s0 + tx;
        Vt[((long)b * 64 + dh) * SP_C + s] = t[tx][ty * 4 + i];
    }
}

// ---------------- generic fp32 [R][C] -> bf16 transposed [C][R] ----------------
__global__ __launch_bounds__(256)
void transcast_kernel(const float* __restrict__ in, ushort* __restrict__ out, int R, int C)
{
    __shared__ float t[32][33];
    int c0 = blockIdx.x * 32, r0 = blockIdx.y * 32;
    int tx = threadIdx.x & 31, ty = threadIdx.x >> 5;
#pragma unroll
    for (int i = 0; i < 4; ++i) {
        int r = r0 + ty * 4 + i, c = c0 + tx;
        float v = 0.f;
        if (r < R && c < C) v = in[(long)r * C + c];
        t[ty * 4 + i][tx] = v;
    }
    __syncthreads();
#pragma unroll
    for (int i = 0; i < 4; ++i) {
        int c = c0 + ty * 4 + i, r = r0 + tx;
        if (c < C && r < R) out[(long)c * R + r] = f2bf(t[tx][ty * 4 + i]);
    }
}

// ---------------- block-diagonal QKV weight (transposed, bf16) + bias ----------------
__global__ __launch_bounds__(256)
void build_wqkvt_kernel(const float* __restrict__ Wq, const float* __restrict__ Wk,
                        const float* __restrict__ Wv, int l, ushort* __restrict__ out)
{
    long idx = (long)blockIdx.x * 256 + threadIdx.x;
    if (idx >= (long)2304 * 768) return;
    int n = (int)(idx / 768), k = (int)(idx % 768);
    int sec = n / 768, hn = (n % 768) / 64, e = n % 64;
    const float* W = sec == 0 ? Wq : (sec == 1 ? Wk : Wv);
    float v = 0.f;
    int d = k - hn * 64;
    if (d >= 0 && d < 64) v = W[(((long)l * NH_ + hn) * 64 + d) * 64 + e];
    out[idx] = f2bf(v);
}

__global__ __launch_bounds__(256)
void build_bqkv_kernel(const float* __restrict__ bq, const float* __restrict__ bk,
                       const float* __restrict__ bv, int l, float* __restrict__ out)
{
    int n = blockIdx.x * 256 + threadIdx.x;
    if (n >= 2304) return;
    int sec = n / 768, h = (n % 768) / 64, e = n % 64;
    const float* b = sec == 0 ? bq : (sec == 1 ? bk : bv);
    out[n] = b[((long)l * NH_ + h) * 64 + e];
}

// ---------------- fp32 GEMM for the tiny head ----------------
template<int BM, int BN, int BK, int TM, int TN>
__global__ __launch_bounds__((BM / TM) * (BN / TN))
void gemm_f32(const float* __restrict__ A, const float* __restrict__ B,
              float* __restrict__ C, const float* __restrict__ bias,
              int M, int N, int K, int lda, int ldb, int ldc)
{
    constexpr int THREADS = (BM / TM) * (BN / TN);
    __shared__ float As[BK][BM + 4];
    __shared__ float Bs[BK][BN + 4];
    const int tid = threadIdx.x;
    const int row0 = blockIdx.y * BM, col0 = blockIdx.x * BN;
    const int tr = tid / (BN / TN), tc = tid % (BN / TN);
    float acc[TM][TN];
#pragma unroll
    for (int i = 0; i < TM; ++i)
#pragma unroll
        for (int j = 0; j < TN; ++j) acc[i][j] = 0.f;
    for (int k0 = 0; k0 < K; k0 += BK) {
#pragma unroll
        for (int it = 0; it < (BM * BK) / THREADS; ++it) {
            int idx = it * THREADS + tid;
            int m = idx / BK, kk = idx % BK;
            int gr = row0 + m, gk = k0 + kk;
            As[kk][m] = (gr < M && gk < K) ? A[(long)gr * lda + gk] : 0.f;
        }
#pragma unroll
        for (int it = 0; it < (BK * BN) / THREADS; ++it) {
            int idx = it * THREADS + tid;
            int kk = idx / BN, nn = idx % BN;
            int gk = k0 + kk, gn = col0 + nn;
            Bs[kk][nn] = (gk < K && gn < N) ? B[(long)gk * ldb + gn] : 0.f;
        }
        __syncthreads();
#pragma unroll
        for (int kk = 0; kk < BK; ++kk) {
            float a[TM], b[TN];
#pragma unroll
            for (int i = 0; i < TM; ++i) a[i] = As[kk][tr * TM + i];
#pragma unroll
            for (int j = 0; j < TN; ++j) b[j] = Bs[kk][tc * TN + j];
#pragma unroll
            for (int i = 0; i < TM; ++i)
#pragma unroll
                for (int j = 0; j < TN; ++j) acc[i][j] = fmaf(a[i], b[j], acc[i][j]);
        }
        __syncthreads();
    }
#pragma unroll
    for (int i = 0; i < TM; ++i) {
        int gr = row0 + tr * TM + i;
        if (gr >= M) continue;
#pragma unroll
        for (int j = 0; j < TN; ++j) {
            int gn = col0 + tc * TN + j;
            if (gn >= N) continue;
            C[(long)gr * ldc + gn] = acc[i][j] + bias[gn];
        }
    }
}

// ---------------- final softmax over 1000 ----------------
__global__ __launch_bounds__(256)
void softmax_out_kernel(const float* __restrict__ logits, float* __restrict__ out)
{
    int row = blockIdx.x;
    int tid = threadIdx.x;
    const float* p = logits + (long)row * OUT_;
    float v[4];
    float mx = -INFINITY;
#pragma unroll
    for (int i = 0; i < 4; ++i) {
        int idx = tid + i * 256;
        v[i] = (idx < OUT_) ? p[idx] : -INFINITY;
        mx = fmaxf(mx, v[i]);
    }
    int wave = tid >> 6, lane = tid & 63;
    for (int off = 32; off > 0; off >>= 1) mx = fmaxf(mx, __shfl_xor(mx, off));
    __shared__ float r1[4], r2[4];
    if (lane == 0) r1[wave] = mx;
    __syncthreads();
    mx = fmaxf(fmaxf(r1[0], r1[1]), fmaxf(r1[2], r1[3]));
    float sum = 0.f;
#pragma unroll
    for (int i = 0; i < 4; ++i) {
        int idx = tid + i * 256;
        if (idx < OUT_) { v[i] = expf(v[i] - mx); sum += v[i]; }
    }
    for (int off = 32; off > 0; off >>= 1) sum += __shfl_xor(sum, off);
    if (lane == 0) r2[wave] = sum;
    __syncthreads();
    sum = r2[0] + r2[1] + r2[2] + r2[3];
    float inv = 1.f / sum;
#pragma unroll
    for (int i = 0; i < 4; ++i) {
        int idx = tid + i * 256;
        if (idx < OUT_) out[(long)row * OUT_ + idx] = v[i] * inv;
    }
}

// ---------------- host driver ----------------
extern "C" void kernel_launch(void* const* d_in, const int* in_sizes, int n_in,
                              void* d_out, int out_size, void* d_ws, size_t ws_size,
                              hipStream_t stream)
{
    const float* images = (const float*)d_in[0];
    const float* W_map  = (const float*)d_in[1];
    const float* b_map  = (const float*)d_in[2];
    const float* cls    = (const float*)d_in[3];
    const float* pos    = (const float*)d_in[4];
    const float* ln1_g  = (const float*)d_in[5];
    const float* ln1_b  = (const float*)d_in[6];
    const float* Wq     = (const float*)d_in[7];
    const float* bq     = (const float*)d_in[8];
    const float* Wk     = (const float*)d_in[9];
    const float* bk     = (const float*)d_in[10];
    const float* Wv     = (const float*)d_in[11];
    const float* bv     = (const float*)d_in[12];
    const float* ln2_g  = (const float*)d_in[13];
    const float* ln2_b  = (const float*)d_in[14];
    const float* W1     = (const float*)d_in[15];
    const float* b1     = (const float*)d_in[16];
    const float* W2     = (const float*)d_in[17];
    const float* b2     = (const float*)d_in[18];
    const float* W_head = (const float*)d_in[19];
    const float* b_head = (const float*)d_in[20];

    char* base = (char*)d_ws;
    float*  x       = (float*)base;   base += (long)RPAD * D_ * 4;        // 19.66 MB
    ushort* hbuf    = (ushort*)base;  base += (long)RPAD * D_ * 2;        //  9.83 MB
    ushort* qkv     = (ushort*)base;  base += (long)RPAD * 2304 * 2;      // 29.49 MB
    ushort* Vt      = (ushort*)base;  base += (long)385 * 64 * SP_C * 2;  // 11.04 MB
    ushort* scoresP = (ushort*)base;  base += (long)384 * SP_R * SP_C * 2;// 44.04 MB
    ushort* mbuf    = (ushort*)base;  base += (long)RPAD * MLP_ * 2;      // 39.32 MB
    ushort* Wmapt   = (ushort*)base;  base += (long)D_ * IND * 2;         //  1.18 MB
    ushort* Wqkvt   = (ushort*)base;  base += (long)2304 * 768 * 2;       //  3.54 MB
    float*  bqkv    = (float*)base;   base += (long)2304 * 4;
    ushort* W1t     = (ushort*)base;  base += (long)MLP_ * D_ * 2;        //  4.72 MB
    ushort* W2t     = (ushort*)base;  base += (long)D_ * MLP_ * 2;        //  4.72 MB
    float*  logits  = (float*)base;   base += (long)N_ * OUT_ * 4;

    // aliases (live only pre-loop)
    float*  tokens  = (float*)scoresP;   // 19.27 MB <= 44 MB
    ushort* patches = mbuf;              //  9.63 MB <= 39 MB

    // ---- patch embedding ----
    transcast_kernel<<<dim3((D_ + 31) / 32, (IND + 31) / 32), 256, 0, stream>>>(W_map, Wmapt, IND, D_);
    {
        long tot = (long)TROWS * IND;
        im2col_kernel<<<(int)((tot + 255) / 256), 256, 0, stream>>>(images, patches);
    }
    mfma_gemm<<<dim3(D_ / 128, TROWS / 128, 1), 256, 0, stream>>>(
        patches, Wmapt, tokens, b_map,
        TROWS, D_, IND, IND, IND, D_,
        0L, 0L, 0L, 0L, 0L, 0L, 1, 1.f, 0, 0, 0);
    {
        long tot = (long)ROWS * D_;
        assemble_kernel<<<(int)((tot + 255) / 256), 256, 0, stream>>>(tokens, cls, pos, x);
    }

    for (int l = 0; l < L_; ++l) {
        layernorm_kernel<<<ROWS, 256, 0, stream>>>(x, hbuf, ln1_g + (long)l * D_, ln1_b + (long)l * D_);

        build_wqkvt_kernel<<<(2304 * 768 + 255) / 256, 256, 0, stream>>>(Wq, Wk, Wv, l, Wqkvt);
        build_bqkv_kernel<<<(2304 + 255) / 256, 256, 0, stream>>>(bq, bk, bv, l, bqkv);

        // QKV: [6304,768] @ blockdiag^T [2304,768] -> qkv bf16
        mfma_gemm<<<dim3(2304 / 128, RPAD / 128, 1), 256, 0, stream>>>(
            hbuf, Wqkvt, qkv, bqkv,
            ROWS, 2304, D_, D_, D_, 2304,
            0L, 0L, 0L, 0L, 0L, 0L, 1, 1.f, 0, 1, 0);

        vtrans_kernel<<<dim3((S_ + 31) / 32, 2, N_ * NH_), 256, 0, stream>>>(qkv, Vt);

        // scores = Q @ K^T / 8 -> bf16 [batch][256][224]
        mfma_gemm<<<dim3(2, 2, N_ * NH_), 256, 0, stream>>>(
            qkv, qkv + 768, scoresP, nullptr,
            S_, S_, DH_, 2304, 2304, SP_C,
            (long)S_ * 2304, 64L, (long)S_ * 2304, 64L,
            (long)NH_ * SP_R * SP_C, (long)SP_R * SP_C,
            NH_, 0.125f, 0, 1, 0);

        softmax197_kernel<<<N_ * NH_ * S_, 64, 0, stream>>>(scoresP);

        // x += P @ V   (per (n,h); heads own disjoint columns)
        mfma_gemm<<<dim3(1, 2, N_ * NH_), 256, 0, stream>>>(
            scoresP, Vt, x, nullptr,
            S_, DH_, SP_C, SP_C, SP_C, D_,
            (long)NH_ * SP_R * SP_C, (long)SP_R * SP_C,
            (long)NH_ * 64 * SP_C, (long)64 * SP_C,
            (long)S_ * D_, 64L,
            NH_, 1.f, 0, 0, 1);

        layernorm_kernel<<<ROWS, 256, 0, stream>>>(x, hbuf, ln2_g + (long)l * D_, ln2_b + (long)l * D_);

        // MLP1: m = gelu(h @ W1 + b1) -> bf16
        transcast_kernel<<<dim3((MLP_ + 31) / 32, (D_ + 31) / 32), 256, 0, stream>>>(
            W1 + (long)l * D_ * MLP_, W1t, D_, MLP_);
        mfma_gemm<<<dim3(MLP_ / 128, RPAD / 128, 1), 256, 0, stream>>>(
            hbuf, W1t, mbuf, b1 + (long)l * MLP_,
            ROWS, MLP_, D_, D_, D_, MLP_,
            0L, 0L, 0L, 0L, 0L, 0L, 1, 1.f, 1, 1, 0);

        // MLP2: x += m @ W2 + b2
        transcast_kernel<<<dim3((D_ + 31) / 32, (MLP_ + 31) / 32), 256, 0, stream>>>(
            W2 + (long)l * MLP_ * D_, W2t, MLP_, D_);
        mfma_gemm<<<dim3(D_ / 128, RPAD / 128, 1), 256, 0, stream>>>(
            mbuf, W2t, x, b2 + (long)l * D_,
            ROWS, D_, MLP_, MLP_, MLP_, D_,
            0L, 0L, 0L, 0L, 0L, 0L, 1, 1.f, 0, 0, 1);
    }

    // head (fp32, tiny): logits = x[:,0,:] @ W_head + b_head
    gemm_f32<64, 64, 16, 4, 4><<<dim3((OUT_ + 63) / 64, 1, 1), 256, 0, stream>>>(
        x, W_head, logits, b_head, N_, OUT_, D_, S_ * D_, OUT_, OUT_);
    softmax_out_kernel<<<N_, 256, 0, stream>>>(logits, (float*)d_out);
}

// Round 4
// 4472.207 us; speedup vs baseline: 11.9887x; 1.1243x over previous
//
#include <hip/hip_runtime.h>
#include <hip/hip_bf16.h>

// ---------------- problem constants ----------------
constexpr int N_   = 32;
constexpr int C_   = 3;
constexpr int P_   = 14;
constexpr int PHW  = 16;
constexpr int IND  = 768;
constexpr int D_   = 768;
constexpr int NH_  = 12;
constexpr int DH_  = 64;
constexpr int L_   = 12;
constexpr int OUT_ = 1000;
constexpr int S_   = 197;
constexpr int MLP_ = 3072;
constexpr int NPATCH = P_ * P_;      // 196
constexpr int ROWS   = N_ * S_;      // 6304
constexpr int TROWS  = N_ * NPATCH;  // 6272
constexpr int RPAD   = 6400;
constexpr int SP_R   = 256;
constexpr int SP_C   = 224;

typedef __attribute__((ext_vector_type(8))) short bf16x8;
typedef __attribute__((ext_vector_type(4))) float f32x4;

__device__ __forceinline__ float bf2f(ushort u) {
    union { float f; unsigned int i; } v; v.i = ((unsigned int)u) << 16; return v.f;
}
__device__ __forceinline__ ushort f2bf(float f) {
    union { float f; unsigned int i; } v; v.f = f;
    unsigned int r = v.i + 0x7fffu + ((v.i >> 16) & 1u);
    return (ushort)(r >> 16);
}

// =================================================================
// bf16 MFMA GEMM (m97-style): C = alpha*A@Bt^T (+bias)(+gelu)(+=C)
// A [M,K] bf16 row-major, Bt [N,K] bf16 row-major.
// 128x128 tile, BK=32, 4 waves, each wave 64x64 via 4x4 16x16x32 MFMA.
// batch z: bi=z/inner, bj=z%inner; ptr += bi*off?1 + bj*off?2.
// =================================================================
__global__ __launch_bounds__(256)
void mfma_gemm(const ushort* __restrict__ Ag,
               const ushort* __restrict__ Bg,
               void* __restrict__ Cg,
               const float* __restrict__ biasg,
               int M, int N, int K,
               int lda, int ldb, int ldc,
               long offA1, long offA2,
               long offB1, long offB2,
               long offC1, long offC2,
               long offS1, long offS2,
               int inner, float alpha, int act, int outbf, int accum)
{
    const int bz = blockIdx.z;
    const int bi = bz / inner, bj = bz % inner;
    const ushort* A = Ag + bi * offA1 + bj * offA2;
    const ushort* B = Bg + bi * offB1 + bj * offB2;
    const long coff = bi * offC1 + bj * offC2;
    const float* bias = biasg ? (biasg + bi * offS1 + bj * offS2) : nullptr;

    __shared__ ushort As[128 * 32];
    __shared__ ushort Bs[128 * 32];

    const int tid  = threadIdx.x;
    const int w    = tid >> 6;
    const int lhi  = (tid & 63) >> 4;
    const int llo  = tid & 15;
    const int wr   = w >> 1, wc = w & 1;
    const int row0 = blockIdx.y * 128;
    const int col0 = blockIdx.x * 128;

    f32x4 acc[4][4];
#pragma unroll
    for (int m = 0; m < 4; ++m)
#pragma unroll
        for (int n = 0; n < 4; ++n) acc[m][n] = (f32x4){0.f, 0.f, 0.f, 0.f};

    int r0s = (0 * 256 + tid) >> 2, s0s = tid & 3;
    int r1s = (1 * 256 + tid) >> 2, s1s = tid & 3;
    int ss0 = s0s ^ ((r0s >> 1) & 3);
    int ss1 = s1s ^ ((r1s >> 1) & 3);
    ushort* dstA0 = As + ((0 * 256 + (w << 6)) << 3);
    ushort* dstA1 = As + ((1 * 256 + (w << 6)) << 3);
    ushort* dstB0 = Bs + ((0 * 256 + (w << 6)) << 3);
    ushort* dstB1 = Bs + ((1 * 256 + (w << 6)) << 3);

    for (int k0 = 0; k0 < K; k0 += 32) {
        const ushort* a0 = A + (long)(row0 + r0s) * lda + k0 + ss0 * 8;
        const ushort* a1 = A + (long)(row0 + r1s) * lda + k0 + ss1 * 8;
        const ushort* b0 = B + (long)(col0 + r0s) * ldb + k0 + ss0 * 8;
        const ushort* b1 = B + (long)(col0 + r1s) * ldb + k0 + ss1 * 8;
        __builtin_amdgcn_global_load_lds((const __attribute__((address_space(1))) void*)a0,
                                         (__attribute__((address_space(3))) void*)dstA0, 16, 0, 0);
        __builtin_amdgcn_global_load_lds((const __attribute__((address_space(1))) void*)a1,
                                         (__attribute__((address_space(3))) void*)dstA1, 16, 0, 0);
        __builtin_amdgcn_global_load_lds((const __attribute__((address_space(1))) void*)b0,
                                         (__attribute__((address_space(3))) void*)dstB0, 16, 0, 0);
        __builtin_amdgcn_global_load_lds((const __attribute__((address_space(1))) void*)b1,
                                         (__attribute__((address_space(3))) void*)dstB1, 16, 0, 0);
        __syncthreads();

        bf16x8 av[4], bv[4];
#pragma unroll
        for (int m = 0; m < 4; ++m) {
            int R = wr * 64 + m * 16 + llo;
            av[m] = *(const bf16x8*)(As + R * 32 + ((lhi ^ ((R >> 1) & 3)) << 3));
        }
#pragma unroll
        for (int n = 0; n < 4; ++n) {
            int R = wc * 64 + n * 16 + llo;
            bv[n] = *(const bf16x8*)(Bs + R * 32 + ((lhi ^ ((R >> 1) & 3)) << 3));
        }
#pragma unroll
        for (int m = 0; m < 4; ++m)
#pragma unroll
            for (int n = 0; n < 4; ++n)
                acc[m][n] = __builtin_amdgcn_mfma_f32_16x16x32_bf16(av[m], bv[n], acc[m][n], 0, 0, 0);
        __syncthreads();
    }

    float* Cf = (float*)Cg + coff;
    ushort* Ch = (ushort*)Cg + coff;
#pragma unroll
    for (int m = 0; m < 4; ++m) {
#pragma unroll
        for (int n = 0; n < 4; ++n) {
#pragma unroll
            for (int j = 0; j < 4; ++j) {
                int gr = row0 + wr * 64 + m * 16 + lhi * 4 + j;
                int gc = col0 + wc * 64 + n * 16 + llo;
                if (gr < M && gc < N) {
                    float v = acc[m][n][j] * alpha;
                    if (bias) v += bias[gc];
                    if (act == 1) v = 0.5f * v * (1.f + erff(v * 0.70710678118654752f));
                    long ci = (long)gr * ldc + gc;
                    if (outbf) {
                        Ch[ci] = f2bf(v);
                    } else {
                        if (accum) v += Cf[ci];
                        Cf[ci] = v;
                    }
                }
            }
        }
    }
}

// ---------------- im2col (patchify) -> bf16 ----------------
__global__ __launch_bounds__(256)
void im2col_kernel(const float* __restrict__ img, ushort* __restrict__ patches)
{
    long idx = (long)blockIdx.x * 256 + threadIdx.x;
    if (idx >= (long)TROWS * IND) return;
    int e = (int)(idx % IND);
    int t = (int)((idx / IND) % NPATCH);
    int n = (int)(idx / ((long)IND * NPATCH));
    int pw = e & 15, ph = (e >> 4) & 15, c = e >> 8;
    int px = t % P_, py = t / P_;
    patches[idx] = f2bf(img[(((long)n * C_ + c) * 224 + py * PHW + ph) * 224 + px * PHW + pw]);
}

// ---------------- assemble x = [cls ; tokens] + pos (fp32) ----------------
__global__ __launch_bounds__(256)
void assemble_kernel(const float* __restrict__ tokens,
                     const float* __restrict__ cls,
                     const float* __restrict__ pos,
                     float* __restrict__ x)
{
    long idx = (long)blockIdx.x * 256 + threadIdx.x;
    if (idx >= (long)ROWS * D_) return;
    int d = (int)(idx % D_);
    int s = (int)((idx / D_) % S_);
    long n = idx / ((long)D_ * S_);
    float v = (s == 0) ? cls[d] : tokens[((long)n * NPATCH + (s - 1)) * D_ + d];
    x[idx] = v + pos[(long)s * D_ + d];
}

// ---------------- layernorm fp32 -> bf16 ----------------
__global__ __launch_bounds__(256)
void layernorm_kernel(const float* __restrict__ x, ushort* __restrict__ out,
                      const float* __restrict__ g, const float* __restrict__ b)
{
    long row = blockIdx.x;
    const float* xr = x + row * D_;
    ushort* orow = out + row * D_;
    int tid = threadIdx.x;
    float v0 = xr[tid], v1 = xr[tid + 256], v2 = xr[tid + 512];
    float s  = v0 + v1 + v2;
    float sq = v0 * v0 + v1 * v1 + v2 * v2;
    for (int off = 32; off > 0; off >>= 1) {
        s  += __shfl_down(s, off);
        sq += __shfl_down(sq, off);
    }
    __shared__ float rs[4], rq[4];
    int wave = tid >> 6, lane = tid & 63;
    if (lane == 0) { rs[wave] = s; rq[wave] = sq; }
    __syncthreads();
    float S  = rs[0] + rs[1] + rs[2] + rs[3];
    float SQ = rq[0] + rq[1] + rq[2] + rq[3];
    float mean = S * (1.f / 768.f);
    float var  = SQ * (1.f / 768.f) - mean * mean;
    float rstd = rsqrtf(var + 1e-5f);
    orow[tid]       = f2bf((v0 - mean) * rstd * g[tid]       + b[tid]);
    orow[tid + 256] = f2bf((v1 - mean) * rstd * g[tid + 256] + b[tid + 256]);
    orow[tid + 512] = f2bf((v2 - mean) * rstd * g[tid + 512] + b[tid + 512]);
}

// ---------------- softmax over 197, 4 rows per block, zero-pad to 224 ----------------
__global__ __launch_bounds__(256)
void softmax197_kernel(ushort* __restrict__ scores)
{
    long rid = (long)blockIdx.x * 4 + (threadIdx.x >> 6);
    if (rid >= (long)N_ * NH_ * S_) return;
    long batch = rid / S_;
    long r = rid % S_;
    ushort* p = scores + (batch * SP_R + r) * SP_C;
    int lane = threadIdx.x & 63;
    float v[4];
    float mx = -INFINITY;
#pragma unroll
    for (int i = 0; i < 4; ++i) {
        int idx = lane + i * 64;
        v[i] = (idx < S_) ? bf2f(p[idx]) : -INFINITY;
        mx = fmaxf(mx, v[i]);
    }
    for (int off = 32; off > 0; off >>= 1) mx = fmaxf(mx, __shfl_xor(mx, off));
    float sum = 0.f;
#pragma unroll
    for (int i = 0; i < 4; ++i) {
        int idx = lane + i * 64;
        if (idx < S_) { v[i] = expf(v[i] - mx); sum += v[i]; }
    }
    for (int off = 32; off > 0; off >>= 1) sum += __shfl_xor(sum, off);
    float inv = 1.f / sum;
#pragma unroll
    for (int i = 0; i < 4; ++i) {
        int idx = lane + i * 64;
        if (idx < SP_C) p[idx] = (idx < S_) ? f2bf(v[i] * inv) : (ushort)0;
    }
}

// ---------------- V transpose: qkv V-section -> Vt [batch][64][224] (zero-padded) ----------------
__global__ __launch_bounds__(256)
void vtrans_kernel(const ushort* __restrict__ qkv, ushort* __restrict__ Vt)
{
    int b = blockIdx.z;
    int n = b / NH_, h = b % NH_;
    __shared__ ushort t[32][33];
    int s0 = blockIdx.x * 32, d0 = blockIdx.y * 32;
    int tx = threadIdx.x & 31, ty = threadIdx.x >> 5;
#pragma unroll
    for (int i = 0; i < 4; ++i) {
        int s = s0 + ty * 4 + i;
        ushort v = 0;
        if (s < S_) v = qkv[(long)(n * S_ + s) * 2304 + 1536 + h * 64 + d0 + tx];
        t[ty * 4 + i][tx] = v;
    }
    __syncthreads();
#pragma unroll
    for (int i = 0; i < 4; ++i) {
        int dh = d0 + ty * 4 + i;
        int s  = s0 + tx;
        Vt[((long)b * 64 + dh) * SP_C + s] = t[tx][ty * 4 + i];
    }
}

// ---------------- fp32 [R][C] -> bf16 transposed [C][R], batched over z (layer) ----------------
__global__ __launch_bounds__(256)
void transcast_kernel(const float* __restrict__ in, ushort* __restrict__ out,
                      int R, int C, long inL, long outL)
{
    const float* ip = in + (long)blockIdx.z * inL;
    ushort* op = out + (long)blockIdx.z * outL;
    __shared__ float t[32][33];
    int c0 = blockIdx.x * 32, r0 = blockIdx.y * 32;
    int tx = threadIdx.x & 31, ty = threadIdx.x >> 5;
#pragma unroll
    for (int i = 0; i < 4; ++i) {
        int r = r0 + ty * 4 + i, c = c0 + tx;
        float v = 0.f;
        if (r < R && c < C) v = ip[(long)r * C + c];
        t[ty * 4 + i][tx] = v;
    }
    __syncthreads();
#pragma unroll
    for (int i = 0; i < 4; ++i) {
        int c = c0 + ty * 4 + i, r = r0 + tx;
        if (c < C && r < R) op[(long)c * R + r] = f2bf(t[tx][ty * 4 + i]);
    }
}

// ---------------- fp32 [R][C] -> fp32 transposed [C][R] ----------------
__global__ __launch_bounds__(256)
void transf32_kernel(const float* __restrict__ in, float* __restrict__ out, int R, int C)
{
    __shared__ float t[32][33];
    int c0 = blockIdx.x * 32, r0 = blockIdx.y * 32;
    int tx = threadIdx.x & 31, ty = threadIdx.x >> 5;
#pragma unroll
    for (int i = 0; i < 4; ++i) {
        int r = r0 + ty * 4 + i, c = c0 + tx;
        float v = 0.f;
        if (r < R && c < C) v = in[(long)r * C + c];
        t[ty * 4 + i][tx] = v;
    }
    __syncthreads();
#pragma unroll
    for (int i = 0; i < 4; ++i) {
        int c = c0 + ty * 4 + i, r = r0 + tx;
        if (c < C && r < R) out[(long)c * R + r] = t[tx][ty * 4 + i];
    }
}

// ---------------- compact per-head transposed QKV weights ----------------
// out[z][sec][h][e][d] (bf16), z-layer stride 36*4096 els. Bt[e][d] = W[l][h][d][e].
__global__ __launch_bounds__(256)
void build_wqkvC_kernel(const float* __restrict__ Wq, const float* __restrict__ Wk,
                        const float* __restrict__ Wv, int l0, ushort* __restrict__ out)
{
    long idx = (long)blockIdx.x * 256 + threadIdx.x;
    if (idx >= 36L * 4096) return;
    int z = blockIdx.z, l = l0 + z;
    int sec = (int)(idx / 49152);
    int r   = (int)(idx % 49152);
    int h = r / 4096, rr = r % 4096, e = rr / 64, d = rr % 64;
    const float* W = sec == 0 ? Wq : (sec == 1 ? Wk : Wv);
    out[(long)z * 147456 + idx] = f2bf(W[(((long)l * NH_ + h) * 64 + d) * 64 + e]);
}

// ---------------- all-layer QKV bias: out[l][sec*768 + h*64 + e] ----------------
__global__ __launch_bounds__(256)
void build_bqkv_kernel(const float* __restrict__ bq, const float* __restrict__ bk,
                       const float* __restrict__ bv, float* __restrict__ out)
{
    int i = blockIdx.x * 256 + threadIdx.x;
    if (i >= L_ * 2304) return;
    int l = i / 2304, n = i % 2304;
    int sec = n / 768, h = (n % 768) / 64, e = n % 64;
    const float* b = sec == 0 ? bq : (sec == 1 ? bk : bv);
    out[i] = b[((long)l * NH_ + h) * 64 + e];
}

// ---------------- head: one wave per (n, c) output ----------------
__global__ __launch_bounds__(256)
void head_kernel(const float* __restrict__ x, const float* __restrict__ Wt,
                 const float* __restrict__ bhead, float* __restrict__ logits)
{
    int wid = blockIdx.x * 4 + (threadIdx.x >> 6);
    int lane = threadIdx.x & 63;
    int n = wid / OUT_, c = wid % OUT_;
    if (n >= N_) return;
    const float* xr = x + (long)n * S_ * D_;   // cls row (s=0)
    const float* wr = Wt + (long)c * D_;
    float acc = 0.f;
#pragma unroll
    for (int i = 0; i < 12; ++i) acc += xr[lane + i * 64] * wr[lane + i * 64];
    for (int off = 32; off > 0; off >>= 1) acc += __shfl_down(acc, off);
    if (lane == 0) logits[(long)n * OUT_ + c] = acc + bhead[c];
}

// ---------------- final softmax over 1000 ----------------
__global__ __launch_bounds__(256)
void softmax_out_kernel(const float* __restrict__ logits, float* __restrict__ out)
{
    int row = blockIdx.x;
    int tid = threadIdx.x;
    const float* p = logits + (long)row * OUT_;
    float v[4];
    float mx = -INFINITY;
#pragma unroll
    for (int i = 0; i < 4; ++i) {
        int idx = tid + i * 256;
        v[i] = (idx < OUT_) ? p[idx] : -INFINITY;
        mx = fmaxf(mx, v[i]);
    }
    int wave = tid >> 6, lane = tid & 63;
    for (int off = 32; off > 0; off >>= 1) mx = fmaxf(mx, __shfl_xor(mx, off));
    __shared__ float r1[4], r2[4];
    if (lane == 0) r1[wave] = mx;
    __syncthreads();
    mx = fmaxf(fmaxf(r1[0], r1[1]), fmaxf(r1[2], r1[3]));
    float sum = 0.f;
#pragma unroll
    for (int i = 0; i < 4; ++i) {
        int idx = tid + i * 256;
        if (idx < OUT_) { v[i] = expf(v[i] - mx); sum += v[i]; }
    }
    for (int off = 32; off > 0; off >>= 1) sum += __shfl_xor(sum, off);
    if (lane == 0) r2[wave] = sum;
    __syncthreads();
    sum = r2[0] + r2[1] + r2[2] + r2[3];
    float inv = 1.f / sum;
#pragma unroll
    for (int i = 0; i < 4; ++i) {
        int idx = tid + i * 256;
        if (idx < OUT_) out[(long)row * OUT_ + idx] = v[i] * inv;
    }
}

// ---------------- host driver ----------------
extern "C" void kernel_launch(void* const* d_in, const int* in_sizes, int n_in,
                              void* d_out, int out_size, void* d_ws, size_t ws_size,
                              hipStream_t stream)
{
    const float* images = (const float*)d_in[0];
    const float* W_map  = (const float*)d_in[1];
    const float* b_map  = (const float*)d_in[2];
    const float* cls    = (const float*)d_in[3];
    const float* pos    = (const float*)d_in[4];
    const float* ln1_g  = (const float*)d_in[5];
    const float* ln1_b  = (const float*)d_in[6];
    const float* Wq     = (const float*)d_in[7];
    const float* bq     = (const float*)d_in[8];
    const float* Wk     = (const float*)d_in[9];
    const float* bk     = (const float*)d_in[10];
    const float* Wv     = (const float*)d_in[11];
    const float* bv     = (const float*)d_in[12];
    const float* ln2_g  = (const float*)d_in[13];
    const float* ln2_b  = (const float*)d_in[14];
    const float* W1     = (const float*)d_in[15];
    const float* b1     = (const float*)d_in[16];
    const float* W2     = (const float*)d_in[17];
    const float* b2     = (const float*)d_in[18];
    const float* W_head = (const float*)d_in[19];
    const float* b_head = (const float*)d_in[20];

    char* base = (char*)d_ws;
    float*  x       = (float*)base;   base += 19660800L;   // 6400*768*4
    ushort* hbuf    = (ushort*)base;  base += 9830400L;    // 6400*768*2
    ushort* qkv     = (ushort*)base;  base += 29491200L;   // 6400*2304*2
    ushort* Vt      = (ushort*)base;  base += 11038720L;   // 385*64*224*2 (1 batch slack)
    ushort* scoresP = (ushort*)base;  base += 44040192L;   // 384*256*224*2
    ushort* mbuf    = (ushort*)base;  base += 39321600L;   // 6400*3072*2
    ushort* Wmapt   = (ushort*)base;  base += 1179648L;    // 768*768*2
    float*  bqkvA   = (float*)base;   base += 110592L;     // 12*2304*4
    ushort* WqkvC   = (ushort*)base;  base += 3538944L;    // 12*36*4096*2 (compact, always)

    // conditional hoist of W1t/W2t for all layers
    size_t used = (size_t)(base - (char*)d_ws);
    const long W1L_ALL = 56623104L, W2L_ALL = 56623104L;   // 12*3072*768*2 each
    const long W1L_ONE = 4718592L,  W2L_ONE = 4718592L;
    bool hoist = ws_size >= used + (size_t)(W1L_ALL + W2L_ALL);
    ushort* W1tA = (ushort*)base;  base += hoist ? W1L_ALL : W1L_ONE;
    ushort* W2tA = (ushort*)base;  base += hoist ? W2L_ALL : W2L_ONE;
    const long w1str = hoist ? 3072L * 768 : 0;
    const long w2str = hoist ? 768L * 3072 : 0;

    // post-loop aliases into scoresP region
    float* W_headT = (float*)scoresP;                       // 1000*768*4 = 3,072,000
    float* logits  = (float*)((char*)scoresP + 3072000L);   // 32*1000*4
    // pre-loop aliases
    float*  tokens  = (float*)scoresP;                      // 6272*768*4 = 19.3 MB
    ushort* patches = mbuf;                                 // 6272*768*2

    // ==== one-time preprocessing ====
    build_wqkvC_kernel<<<dim3(576, 1, L_), 256, 0, stream>>>(Wq, Wk, Wv, 0, WqkvC);
    build_bqkv_kernel<<<(L_ * 2304 + 255) / 256, 256, 0, stream>>>(bq, bk, bv, bqkvA);
    transcast_kernel<<<dim3(24, 24, 1), 256, 0, stream>>>(W_map, Wmapt, IND, D_, 0L, 0L);
    if (hoist) {
        transcast_kernel<<<dim3(96, 24, L_), 256, 0, stream>>>(W1, W1tA, D_, MLP_,
                                                               (long)D_ * MLP_, 3072L * 768);
        transcast_kernel<<<dim3(24, 96, L_), 256, 0, stream>>>(W2, W2tA, MLP_, D_,
                                                               (long)MLP_ * D_, 768L * 3072);
    }

    // ==== patch embedding ====
    {
        long tot = (long)TROWS * IND;
        im2col_kernel<<<(int)((tot + 255) / 256), 256, 0, stream>>>(images, patches);
    }
    mfma_gemm<<<dim3(D_ / 128, TROWS / 128, 1), 256, 0, stream>>>(
        patches, Wmapt, tokens, b_map,
        TROWS, D_, IND, IND, IND, D_,
        0L, 0L, 0L, 0L, 0L, 0L, 0L, 0L, 1, 1.f, 0, 0, 0);
    {
        long tot = (long)ROWS * D_;
        assemble_kernel<<<(int)((tot + 255) / 256), 256, 0, stream>>>(tokens, cls, pos, x);
    }

    for (int l = 0; l < L_; ++l) {
        layernorm_kernel<<<ROWS, 256, 0, stream>>>(x, hbuf, ln1_g + (long)l * D_, ln1_b + (long)l * D_);

        // QKV compact batched: z = sec*12 + h; M=6304, N=64, K=64
        mfma_gemm<<<dim3(1, RPAD / 128, 36), 256, 0, stream>>>(
            hbuf, WqkvC + (long)l * 147456, qkv, bqkvA + (long)l * 2304,
            ROWS, 64, 64, D_, 64, 2304,
            0L, 64L,                 // A: + h*64 column slice
            12L * 4096, 4096L,       // B: sec, head blocks
            768L, 64L,               // C: sec section, head cols
            768L, 64L,               // bias
            12, 1.f, 0, 1, 0);

        vtrans_kernel<<<dim3(7, 2, N_ * NH_), 256, 0, stream>>>(qkv, Vt);

        // scores = Q @ K^T / 8 -> bf16 [batch][256][224]
        mfma_gemm<<<dim3(2, 2, N_ * NH_), 256, 0, stream>>>(
            qkv, qkv + 768, scoresP, nullptr,
            S_, S_, DH_, 2304, 2304, SP_C,
            (long)S_ * 2304, 64L, (long)S_ * 2304, 64L,
            (long)NH_ * SP_R * SP_C, (long)SP_R * SP_C, 0L, 0L,
            NH_, 0.125f, 0, 1, 0);

        softmax197_kernel<<<(N_ * NH_ * S_ + 3) / 4, 256, 0, stream>>>(scoresP);

        // x += P @ V   (per (n,h); heads own disjoint columns)
        mfma_gemm<<<dim3(1, 2, N_ * NH_), 256, 0, stream>>>(
            scoresP, Vt, x, nullptr,
            S_, DH_, SP_C, SP_C, SP_C, D_,
            (long)NH_ * SP_R * SP_C, (long)SP_R * SP_C,
            (long)NH_ * 64 * SP_C, (long)64 * SP_C,
            (long)S_ * D_, 64L, 0L, 0L,
            NH_, 1.f, 0, 0, 1);

        layernorm_kernel<<<ROWS, 256, 0, stream>>>(x, hbuf, ln2_g + (long)l * D_, ln2_b + (long)l * D_);

        // MLP1: m = gelu(h @ W1 + b1) -> bf16
        if (!hoist)
            transcast_kernel<<<dim3(96, 24, 1), 256, 0, stream>>>(
                W1 + (long)l * D_ * MLP_, W1tA, D_, MLP_, 0L, 0L);
        mfma_gemm<<<dim3(MLP_ / 128, RPAD / 128, 1), 256, 0, stream>>>(
            hbuf, W1tA + (long)l * w1str, mbuf, b1 + (long)l * MLP_,
            ROWS, MLP_, D_, D_, D_, MLP_,
            0L, 0L, 0L, 0L, 0L, 0L, 0L, 0L, 1, 1.f, 1, 1, 0);

        // MLP2: x += m @ W2 + b2
        if (!hoist)
            transcast_kernel<<<dim3(24, 96, 1), 256, 0, stream>>>(
                W2 + (long)l * MLP_ * D_, W2tA, MLP_, D_, 0L, 0L);
        mfma_gemm<<<dim3(D_ / 128, RPAD / 128, 1), 256, 0, stream>>>(
            mbuf, W2tA + (long)l * w2str, x, b2 + (long)l * D_,
            ROWS, D_, MLP_, MLP_, MLP_, D_,
            0L, 0L, 0L, 0L, 0L, 0L, 0L, 0L, 1, 1.f, 0, 0, 1);
    }

    // ==== head: logits = x[:,0,:] @ W_head + b_head, then softmax ====
    transf32_kernel<<<dim3(32, 24), 256, 0, stream>>>(W_head, W_headT, D_, OUT_);
    head_kernel<<<(N_ * OUT_) / 4, 256, 0, stream>>>(x, W_headT, b_head, logits);
    softmax_out_kernel<<<N_, 256, 0, stream>>>(logits, (float*)d_out);
}

// Round 5
// 4304.605 us; speedup vs baseline: 12.4554x; 1.0389x over previous
//
#include <hip/hip_runtime.h>
#include <hip/hip_bf16.h>

// ---------------- problem constants ----------------
constexpr int N_   = 32;
constexpr int C_   = 3;
constexpr int P_   = 14;
constexpr int PHW  = 16;
constexpr int IND  = 768;
constexpr int D_   = 768;
constexpr int NH_  = 12;
constexpr int DH_  = 64;
constexpr int L_   = 12;
constexpr int OUT_ = 1000;
constexpr int S_   = 197;
constexpr int MLP_ = 3072;
constexpr int NPATCH = P_ * P_;      // 196
constexpr int ROWS   = N_ * S_;      // 6304
constexpr int TROWS  = N_ * NPATCH;  // 6272
constexpr int RPAD   = 6400;
constexpr int SP_R   = 256;
constexpr int SP_C   = 224;

typedef __attribute__((ext_vector_type(8))) short bf16x8;
typedef __attribute__((ext_vector_type(4))) float f32x4;

__device__ __forceinline__ float bf2f(ushort u) {
    union { float f; unsigned int i; } v; v.i = ((unsigned int)u) << 16; return v.f;
}
__device__ __forceinline__ ushort f2bf(float f) {
    union { float f; unsigned int i; } v; v.f = f;
    unsigned int r = v.i + 0x7fffu + ((v.i >> 16) & 1u);
    return (ushort)(r >> 16);
}

// =================================================================
// bf16 MFMA GEMM, 2-phase double-buffered pipeline (T3-min + T4):
//   - LDS dbuf 2x(128x32) per operand (32 KB)
//   - issue next K-tile's global_load_lds BEFORE computing current
//   - counted s_waitcnt vmcnt(4) + RAW s_barrier (no implicit drain)
// A [M,K] bf16 row-major, Bt [N,K] bf16 row-major.
// 128x128 tile, BK=32, 4 waves, each wave 64x64 via 4x4 16x16x32 MFMA.
// batch z: bi=z/inner, bj=z%inner; ptr += bi*off?1 + bj*off?2.
// swz: XCD-bijective remap of (x,y) for L2 A-panel locality (z==1 grids).
// vtout: if set and bi==2 (QKV V-section), write transposed to Vt[b][dh][s].
// =================================================================
__global__ __launch_bounds__(256)
void mfma_gemm(const ushort* __restrict__ Ag,
               const ushort* __restrict__ Bg,
               void* __restrict__ Cg,
               const float* __restrict__ biasg,
               int M, int N, int K,
               int lda, int ldb, int ldc,
               long offA1, long offA2,
               long offB1, long offB2,
               long offC1, long offC2,
               long offS1, long offS2,
               int inner, float alpha, int act, int outbf, int accum,
               int swz, ushort* __restrict__ vtout)
{
    const int bz = blockIdx.z;
    const int bi = bz / inner, bj = bz % inner;
    const ushort* A = Ag + bi * offA1 + bj * offA2;
    const ushort* B = Bg + bi * offB1 + bj * offB2;
    const long coff = bi * offC1 + bj * offC2;
    const float* bias = biasg ? (biasg + bi * offS1 + bj * offS2) : nullptr;

    int bx = blockIdx.x, by = blockIdx.y;
    if (swz) {
        const int gx = gridDim.x;
        const int nwg = gx * gridDim.y;
        const int orig = by * gx + bx;
        const int q = nwg >> 3, r = nwg & 7;
        const int xcd = orig & 7, loc = orig >> 3;
        const int wgid = (xcd < r ? xcd * (q + 1) : r * (q + 1) + (xcd - r) * q) + loc;
        bx = wgid % gx;
        by = wgid / gx;
    }

    __shared__ ushort As[2][128 * 32];
    __shared__ ushort Bs[2][128 * 32];

    const int tid  = threadIdx.x;
    const int w    = tid >> 6;
    const int lhi  = (tid & 63) >> 4;
    const int llo  = tid & 15;
    const int wr   = w >> 1, wc = w & 1;
    const int row0 = by * 128;
    const int col0 = bx * 128;

    f32x4 acc[4][4];
#pragma unroll
    for (int m = 0; m < 4; ++m)
#pragma unroll
        for (int n = 0; n < 4; ++n) acc[m][n] = (f32x4){0.f, 0.f, 0.f, 0.f};

    // staging geometry: chunk c = it*256+tid; row=c>>2, slot=c&3.
    // LDS physical (row, slot) holds global (row, slot ^ ((row>>1)&3)).
    const int r0s = tid >> 2,        s0s = tid & 3;
    const int r1s = 64 + (tid >> 2), s1s = tid & 3;
    const int ss0 = s0s ^ ((r0s >> 1) & 3);
    const int ss1 = s1s ^ ((r1s >> 1) & 3);
    const int dst0 = (w << 6) << 3;          // chunk base (ushorts) for load 0
    const int dst1 = (256 + (w << 6)) << 3;  // for load 1

    const long arow0 = (long)(row0 + r0s) * lda + ss0 * 8;
    const long arow1 = (long)(row0 + r1s) * lda + ss1 * 8;
    const long brow0 = (long)(col0 + r0s) * ldb + ss0 * 8;
    const long brow1 = (long)(col0 + r1s) * ldb + ss1 * 8;

#define STAGE(buf, k0)                                                                     \
    do {                                                                                   \
        __builtin_amdgcn_global_load_lds(                                                  \
            (const __attribute__((address_space(1))) void*)(A + arow0 + (k0)),             \
            (__attribute__((address_space(3))) void*)(&As[buf][0] + dst0), 16, 0, 0);      \
        __builtin_amdgcn_global_load_lds(                                                  \
            (const __attribute__((address_space(1))) void*)(A + arow1 + (k0)),             \
            (__attribute__((address_space(3))) void*)(&As[buf][0] + dst1), 16, 0, 0);      \
        __builtin_amdgcn_global_load_lds(                                                  \
            (const __attribute__((address_space(1))) void*)(B + brow0 + (k0)),             \
            (__attribute__((address_space(3))) void*)(&Bs[buf][0] + dst0), 16, 0, 0);      \
        __builtin_amdgcn_global_load_lds(                                                  \
            (const __attribute__((address_space(1))) void*)(B + brow1 + (k0)),             \
            (__attribute__((address_space(3))) void*)(&Bs[buf][0] + dst1), 16, 0, 0);      \
    } while (0)

    const int nt = K >> 5;
    STAGE(0, 0);
    for (int t = 0; t < nt; ++t) {
        const int cur = t & 1;
        if (t + 1 < nt) {
            STAGE(cur ^ 1, (t + 1) << 5);
            asm volatile("s_waitcnt vmcnt(4)" ::: "memory");  // oldest 4 (cur buf) done
        } else {
            asm volatile("s_waitcnt vmcnt(0)" ::: "memory");
        }
        __builtin_amdgcn_s_barrier();       // raw: no implicit drain
        asm volatile("" ::: "memory");

        bf16x8 av[4], bv[4];
#pragma unroll
        for (int m = 0; m < 4; ++m) {
            int R = wr * 64 + m * 16 + llo;
            av[m] = *(const bf16x8*)(&As[cur][0] + R * 32 + ((lhi ^ ((R >> 1) & 3)) << 3));
        }
#pragma unroll
        for (int n = 0; n < 4; ++n) {
            int R = wc * 64 + n * 16 + llo;
            bv[n] = *(const bf16x8*)(&Bs[cur][0] + R * 32 + ((lhi ^ ((R >> 1) & 3)) << 3));
        }
#pragma unroll
        for (int m = 0; m < 4; ++m)
#pragma unroll
            for (int n = 0; n < 4; ++n)
                acc[m][n] = __builtin_amdgcn_mfma_f32_16x16x32_bf16(av[m], bv[n], acc[m][n], 0, 0, 0);

        asm volatile("" ::: "memory");
        __builtin_amdgcn_s_barrier();       // reads of cur done before next STAGE overwrites
    }
#undef STAGE

    // epilogue
    float* Cf = (float*)Cg + coff;
    ushort* Ch = (ushort*)Cg + coff;
    const bool vpath = (vtout != nullptr) && (bi == 2);
#pragma unroll
    for (int m = 0; m < 4; ++m) {
#pragma unroll
        for (int n = 0; n < 4; ++n) {
#pragma unroll
            for (int j = 0; j < 4; ++j) {
                int gr = row0 + wr * 64 + m * 16 + lhi * 4 + j;
                int gc = col0 + wc * 64 + n * 16 + llo;
                if (gr >= M || gc >= N) continue;
                float v = acc[m][n][j] * alpha;
                if (bias) v += bias[gc];
                if (act == 1) v = 0.5f * v * (1.f + erff(v * 0.70710678118654752f));
                if (vpath) {
                    int nn = gr / 197, s = gr - nn * 197;
                    vtout[(((long)nn * NH_ + bj) * 64 + gc) * SP_C + s] = f2bf(v);
                } else {
                    long ci = (long)gr * ldc + gc;
                    if (outbf) {
                        Ch[ci] = f2bf(v);
                    } else {
                        if (accum) v += Cf[ci];
                        Cf[ci] = v;
                    }
                }
            }
        }
    }
}

// ---------------- im2col (patchify) -> bf16 ----------------
__global__ __launch_bounds__(256)
void im2col_kernel(const float* __restrict__ img, ushort* __restrict__ patches)
{
    long idx = (long)blockIdx.x * 256 + threadIdx.x;
    if (idx >= (long)TROWS * IND) return;
    int e = (int)(idx % IND);
    int t = (int)((idx / IND) % NPATCH);
    int n = (int)(idx / ((long)IND * NPATCH));
    int pw = e & 15, ph = (e >> 4) & 15, c = e >> 8;
    int px = t % P_, py = t / P_;
    patches[idx] = f2bf(img[(((long)n * C_ + c) * 224 + py * PHW + ph) * 224 + px * PHW + pw]);
}

// ---------------- assemble x = [cls ; tokens] + pos (fp32) ----------------
__global__ __launch_bounds__(256)
void assemble_kernel(const float* __restrict__ tokens,
                     const float* __restrict__ cls,
                     const float* __restrict__ pos,
                     float* __restrict__ x)
{
    long idx = (long)blockIdx.x * 256 + threadIdx.x;
    if (idx >= (long)ROWS * D_) return;
    int d = (int)(idx % D_);
    int s = (int)((idx / D_) % S_);
    long n = idx / ((long)D_ * S_);
    float v = (s == 0) ? cls[d] : tokens[((long)n * NPATCH + (s - 1)) * D_ + d];
    x[idx] = v + pos[(long)s * D_ + d];
}

// ---------------- layernorm fp32 -> bf16 ----------------
__global__ __launch_bounds__(256)
void layernorm_kernel(const float* __restrict__ x, ushort* __restrict__ out,
                      const float* __restrict__ g, const float* __restrict__ b)
{
    long row = blockIdx.x;
    const float* xr = x + row * D_;
    ushort* orow = out + row * D_;
    int tid = threadIdx.x;
    float v0 = xr[tid], v1 = xr[tid + 256], v2 = xr[tid + 512];
    float s  = v0 + v1 + v2;
    float sq = v0 * v0 + v1 * v1 + v2 * v2;
    for (int off = 32; off > 0; off >>= 1) {
        s  += __shfl_down(s, off);
        sq += __shfl_down(sq, off);
    }
    __shared__ float rs[4], rq[4];
    int wave = tid >> 6, lane = tid & 63;
    if (lane == 0) { rs[wave] = s; rq[wave] = sq; }
    __syncthreads();
    float S  = rs[0] + rs[1] + rs[2] + rs[3];
    float SQ = rq[0] + rq[1] + rq[2] + rq[3];
    float mean = S * (1.f / 768.f);
    float var  = SQ * (1.f / 768.f) - mean * mean;
    float rstd = rsqrtf(var + 1e-5f);
    orow[tid]       = f2bf((v0 - mean) * rstd * g[tid]       + b[tid]);
    orow[tid + 256] = f2bf((v1 - mean) * rstd * g[tid + 256] + b[tid + 256]);
    orow[tid + 512] = f2bf((v2 - mean) * rstd * g[tid + 512] + b[tid + 512]);
}

// ---------------- softmax over 197, 4 rows per block, zero-pad to 224 ----------------
__global__ __launch_bounds__(256)
void softmax197_kernel(ushort* __restrict__ scores)
{
    long rid = (long)blockIdx.x * 4 + (threadIdx.x >> 6);
    if (rid >= (long)N_ * NH_ * S_) return;
    long batch = rid / S_;
    long r = rid % S_;
    ushort* p = scores + (batch * SP_R + r) * SP_C;
    int lane = threadIdx.x & 63;
    float v[4];
    float mx = -INFINITY;
#pragma unroll
    for (int i = 0; i < 4; ++i) {
        int idx = lane + i * 64;
        v[i] = (idx < S_) ? bf2f(p[idx]) : -INFINITY;
        mx = fmaxf(mx, v[i]);
    }
    for (int off = 32; off > 0; off >>= 1) mx = fmaxf(mx, __shfl_xor(mx, off));
    float sum = 0.f;
#pragma unroll
    for (int i = 0; i < 4; ++i) {
        int idx = lane + i * 64;
        if (idx < S_) { v[i] = expf(v[i] - mx); sum += v[i]; }
    }
    for (int off = 32; off > 0; off >>= 1) sum += __shfl_xor(sum, off);
    float inv = 1.f / sum;
#pragma unroll
    for (int i = 0; i < 4; ++i) {
        int idx = lane + i * 64;
        if (idx < SP_C) p[idx] = (idx < S_) ? f2bf(v[i] * inv) : (ushort)0;
    }
}

// ---------------- fp32 [R][C] -> bf16 transposed [C][R], batched over z (layer) ----------------
__global__ __launch_bounds__(256)
void transcast_kernel(const float* __restrict__ in, ushort* __restrict__ out,
                      int R, int C, long inL, long outL)
{
    const float* ip = in + (long)blockIdx.z * inL;
    ushort* op = out + (long)blockIdx.z * outL;
    __shared__ float t[32][33];
    int c0 = blockIdx.x * 32, r0 = blockIdx.y * 32;
    int tx = threadIdx.x & 31, ty = threadIdx.x >> 5;
#pragma unroll
    for (int i = 0; i < 4; ++i) {
        int r = r0 + ty * 4 + i, c = c0 + tx;
        float v = 0.f;
        if (r < R && c < C) v = ip[(long)r * C + c];
        t[ty * 4 + i][tx] = v;
    }
    __syncthreads();
#pragma unroll
    for (int i = 0; i < 4; ++i) {
        int c = c0 + ty * 4 + i, r = r0 + tx;
        if (c < C && r < R) op[(long)c * R + r] = f2bf(t[tx][ty * 4 + i]);
    }
}

// ---------------- fp32 [R][C] -> fp32 transposed [C][R] ----------------
__global__ __launch_bounds__(256)
void transf32_kernel(const float* __restrict__ in, float* __restrict__ out, int R, int C)
{
    __shared__ float t[32][33];
    int c0 = blockIdx.x * 32, r0 = blockIdx.y * 32;
    int tx = threadIdx.x & 31, ty = threadIdx.x >> 5;
#pragma unroll
    for (int i = 0; i < 4; ++i) {
        int r = r0 + ty * 4 + i, c = c0 + tx;
        float v = 0.f;
        if (r < R && c < C) v = in[(long)r * C + c];
        t[ty * 4 + i][tx] = v;
    }
    __syncthreads();
#pragma unroll
    for (int i = 0; i < 4; ++i) {
        int c = c0 + ty * 4 + i, r = r0 + tx;
        if (c < C && r < R) out[(long)c * R + r] = t[tx][ty * 4 + i];
    }
}

// ---------------- compact per-head transposed QKV weights ----------------
// out[z][sec][h][e][d] (bf16), z-layer stride 36*4096 els. Bt[e][d] = W[l][h][d][e].
__global__ __launch_bounds__(256)
void build_wqkvC_kernel(const float* __restrict__ Wq, const float* __restrict__ Wk,
                        const float* __restrict__ Wv, int l0, ushort* __restrict__ out)
{
    long idx = (long)blockIdx.x * 256 + threadIdx.x;
    if (idx >= 36L * 4096) return;
    int z = blockIdx.z, l = l0 + z;
    int sec = (int)(idx / 49152);
    int r   = (int)(idx % 49152);
    int h = r / 4096, rr = r % 4096, e = rr / 64, d = rr % 64;
    const float* W = sec == 0 ? Wq : (sec == 1 ? Wk : Wv);
    out[(long)z * 147456 + idx] = f2bf(W[(((long)l * NH_ + h) * 64 + d) * 64 + e]);
}

// ---------------- all-layer QKV bias: out[l][sec*768 + h*64 + e] ----------------
__global__ __launch_bounds__(256)
void build_bqkv_kernel(const float* __restrict__ bq, const float* __restrict__ bk,
                       const float* __restrict__ bv, float* __restrict__ out)
{
    int i = blockIdx.x * 256 + threadIdx.x;
    if (i >= L_ * 2304) return;
    int l = i / 2304, n = i % 2304;
    int sec = n / 768, h = (n % 768) / 64, e = n % 64;
    const float* b = sec == 0 ? bq : (sec == 1 ? bk : bv);
    out[i] = b[((long)l * NH_ + h) * 64 + e];
}

// ---------------- head: one wave per (n, c) output ----------------
__global__ __launch_bounds__(256)
void head_kernel(const float* __restrict__ x, const float* __restrict__ Wt,
                 const float* __restrict__ bhead, float* __restrict__ logits)
{
    int wid = blockIdx.x * 4 + (threadIdx.x >> 6);
    int lane = threadIdx.x & 63;
    int n = wid / OUT_, c = wid % OUT_;
    if (n >= N_) return;
    const float* xr = x + (long)n * S_ * D_;   // cls row (s=0)
    const float* wr = Wt + (long)c * D_;
    float acc = 0.f;
#pragma unroll
    for (int i = 0; i < 12; ++i) acc += xr[lane + i * 64] * wr[lane + i * 64];
    for (int off = 32; off > 0; off >>= 1) acc += __shfl_down(acc, off);
    if (lane == 0) logits[(long)n * OUT_ + c] = acc + bhead[c];
}

// ---------------- final softmax over 1000 ----------------
__global__ __launch_bounds__(256)
void softmax_out_kernel(const float* __restrict__ logits, float* __restrict__ out)
{
    int row = blockIdx.x;
    int tid = threadIdx.x;
    const float* p = logits + (long)row * OUT_;
    float v[4];
    float mx = -INFINITY;
#pragma unroll
    for (int i = 0; i < 4; ++i) {
        int idx = tid + i * 256;
        v[i] = (idx < OUT_) ? p[idx] : -INFINITY;
        mx = fmaxf(mx, v[i]);
    }
    int wave = tid >> 6, lane = tid & 63;
    for (int off = 32; off > 0; off >>= 1) mx = fmaxf(mx, __shfl_xor(mx, off));
    __shared__ float r1[4], r2[4];
    if (lane == 0) r1[wave] = mx;
    __syncthreads();
    mx = fmaxf(fmaxf(r1[0], r1[1]), fmaxf(r1[2], r1[3]));
    float sum = 0.f;
#pragma unroll
    for (int i = 0; i < 4; ++i) {
        int idx = tid + i * 256;
        if (idx < OUT_) { v[i] = expf(v[i] - mx); sum += v[i]; }
    }
    for (int off = 32; off > 0; off >>= 1) sum += __shfl_xor(sum, off);
    if (lane == 0) r2[wave] = sum;
    __syncthreads();
    sum = r2[0] + r2[1] + r2[2] + r2[3];
    float inv = 1.f / sum;
#pragma unroll
    for (int i = 0; i < 4; ++i) {
        int idx = tid + i * 256;
        if (idx < OUT_) out[(long)row * OUT_ + idx] = v[i] * inv;
    }
}

// ---------------- host driver ----------------
extern "C" void kernel_launch(void* const* d_in, const int* in_sizes, int n_in,
                              void* d_out, int out_size, void* d_ws, size_t ws_size,
                              hipStream_t stream)
{
    const float* images = (const float*)d_in[0];
    const float* W_map  = (const float*)d_in[1];
    const float* b_map  = (const float*)d_in[2];
    const float* cls    = (const float*)d_in[3];
    const float* pos    = (const float*)d_in[4];
    const float* ln1_g  = (const float*)d_in[5];
    const float* ln1_b  = (const float*)d_in[6];
    const float* Wq     = (const float*)d_in[7];
    const float* bq     = (const float*)d_in[8];
    const float* Wk     = (const float*)d_in[9];
    const float* bk     = (const float*)d_in[10];
    const float* Wv     = (const float*)d_in[11];
    const float* bv     = (const float*)d_in[12];
    const float* ln2_g  = (const float*)d_in[13];
    const float* ln2_b  = (const float*)d_in[14];
    const float* W1     = (const float*)d_in[15];
    const float* b1     = (const float*)d_in[16];
    const float* W2     = (const float*)d_in[17];
    const float* b2     = (const float*)d_in[18];
    const float* W_head = (const float*)d_in[19];
    const float* b_head = (const float*)d_in[20];

    char* base = (char*)d_ws;
    float*  x       = (float*)base;   base += 19660800L;   // 6400*768*4
    ushort* hbuf    = (ushort*)base;  base += 9830400L;    // 6400*768*2
    ushort* qkv     = (ushort*)base;  base += 29491200L;   // 6400*2304*2
    ushort* Vt      = (ushort*)base;  base += 11038720L;   // 385*64*224*2 (1 batch slack)
    ushort* scoresP = (ushort*)base;  base += 44040192L;   // 384*256*224*2
    ushort* mbuf    = (ushort*)base;  base += 39321600L;   // 6400*3072*2
    ushort* Wmapt   = (ushort*)base;  base += 1179648L;    // 768*768*2
    float*  bqkvA   = (float*)base;   base += 110592L;     // 12*2304*4
    ushort* WqkvC   = (ushort*)base;  base += 3538944L;    // 12*36*4096*2

    size_t used = (size_t)(base - (char*)d_ws);
    const long W1L_ALL = 56623104L, W2L_ALL = 56623104L;   // 12*3072*768*2 each
    const long W1L_ONE = 4718592L,  W2L_ONE = 4718592L;
    bool hoist = ws_size >= used + (size_t)(W1L_ALL + W2L_ALL);
    ushort* W1tA = (ushort*)base;  base += hoist ? W1L_ALL : W1L_ONE;
    ushort* W2tA = (ushort*)base;  base += hoist ? W2L_ALL : W2L_ONE;
    const long w1str = hoist ? 3072L * 768 : 0;
    const long w2str = hoist ? 768L * 3072 : 0;

    // post-loop aliases into scoresP region
    float* W_headT = (float*)scoresP;                       // 1000*768*4
    float* logits  = (float*)((char*)scoresP + 3072000L);   // 32*1000*4
    // pre-loop aliases
    float*  tokens  = (float*)scoresP;                      // 6272*768*4
    ushort* patches = mbuf;                                 // 6272*768*2

    // ==== one-time preprocessing ====
    build_wqkvC_kernel<<<dim3(576, 1, L_), 256, 0, stream>>>(Wq, Wk, Wv, 0, WqkvC);
    build_bqkv_kernel<<<(L_ * 2304 + 255) / 256, 256, 0, stream>>>(bq, bk, bv, bqkvA);
    transcast_kernel<<<dim3(24, 24, 1), 256, 0, stream>>>(W_map, Wmapt, IND, D_, 0L, 0L);
    if (hoist) {
        transcast_kernel<<<dim3(96, 24, L_), 256, 0, stream>>>(W1, W1tA, D_, MLP_,
                                                               (long)D_ * MLP_, 3072L * 768);
        transcast_kernel<<<dim3(24, 96, L_), 256, 0, stream>>>(W2, W2tA, MLP_, D_,
                                                               (long)MLP_ * D_, 768L * 3072);
    }

    // ==== patch embedding ====
    {
        long tot = (long)TROWS * IND;
        im2col_kernel<<<(int)((tot + 255) / 256), 256, 0, stream>>>(images, patches);
    }
    mfma_gemm<<<dim3(D_ / 128, TROWS / 128, 1), 256, 0, stream>>>(
        patches, Wmapt, tokens, b_map,
        TROWS, D_, IND, IND, IND, D_,
        0L, 0L, 0L, 0L, 0L, 0L, 0L, 0L, 1, 1.f, 0, 0, 0, 1, nullptr);
    {
        long tot = (long)ROWS * D_;
        assemble_kernel<<<(int)((tot + 255) / 256), 256, 0, stream>>>(tokens, cls, pos, x);
    }

    for (int l = 0; l < L_; ++l) {
        layernorm_kernel<<<ROWS, 256, 0, stream>>>(x, hbuf, ln1_g + (long)l * D_, ln1_b + (long)l * D_);

        // QKV compact batched: z = sec*12 + h; M=6304, N=64, K=64.
        // sec==2 (V) writes transposed straight into Vt (pads multiply by softmax zeros).
        mfma_gemm<<<dim3(1, RPAD / 128, 36), 256, 0, stream>>>(
            hbuf, WqkvC + (long)l * 147456, qkv, bqkvA + (long)l * 2304,
            ROWS, 64, 64, D_, 64, 2304,
            0L, 64L,
            12L * 4096, 4096L,
            768L, 64L,
            768L, 64L,
            12, 1.f, 0, 1, 0, 0, Vt);

        // scores = Q @ K^T / 8 -> bf16 [batch][256][224]
        mfma_gemm<<<dim3(2, 2, N_ * NH_), 256, 0, stream>>>(
            qkv, qkv + 768, scoresP, nullptr,
            S_, S_, DH_, 2304, 2304, SP_C,
            (long)S_ * 2304, 64L, (long)S_ * 2304, 64L,
            (long)NH_ * SP_R * SP_C, (long)SP_R * SP_C, 0L, 0L,
            NH_, 0.125f, 0, 1, 0, 0, nullptr);

        softmax197_kernel<<<(N_ * NH_ * S_ + 3) / 4, 256, 0, stream>>>(scoresP);

        // x += P @ V   (per (n,h); heads own disjoint columns)
        mfma_gemm<<<dim3(1, 2, N_ * NH_), 256, 0, stream>>>(
            scoresP, Vt, x, nullptr,
            S_, DH_, SP_C, SP_C, SP_C, D_,
            (long)NH_ * SP_R * SP_C, (long)SP_R * SP_C,
            (long)NH_ * 64 * SP_C, (long)64 * SP_C,
            (long)S_ * D_, 64L, 0L, 0L,
            NH_, 1.f, 0, 0, 1, 0, nullptr);

        layernorm_kernel<<<ROWS, 256, 0, stream>>>(x, hbuf, ln2_g + (long)l * D_, ln2_b + (long)l * D_);

        // MLP1: m = gelu(h @ W1 + b1) -> bf16
        if (!hoist)
            transcast_kernel<<<dim3(96, 24, 1), 256, 0, stream>>>(
                W1 + (long)l * D_ * MLP_, W1tA, D_, MLP_, 0L, 0L);
        mfma_gemm<<<dim3(MLP_ / 128, RPAD / 128, 1), 256, 0, stream>>>(
            hbuf, W1tA + (long)l * w1str, mbuf, b1 + (long)l * MLP_,
            ROWS, MLP_, D_, D_, D_, MLP_,
            0L, 0L, 0L, 0L, 0L, 0L, 0L, 0L, 1, 1.f, 1, 1, 0, 1, nullptr);

        // MLP2: x += m @ W2 + b2
        if (!hoist)
            transcast_kernel<<<dim3(24, 96, 1), 256, 0, stream>>>(
                W2 + (long)l * MLP_ * D_, W2tA, MLP_, D_, 0L, 0L);
        mfma_gemm<<<dim3(D_ / 128, RPAD / 128, 1), 256, 0, stream>>>(
            mbuf, W2tA + (long)l * w2str, x, b2 + (long)l * D_,
            ROWS, D_, MLP_, MLP_, MLP_, D_,
            0L, 0L, 0L, 0L, 0L, 0L, 0L, 0L, 1, 1.f, 0, 0, 1, 1, nullptr);
    }

    // ==== head: logits = x[:,0,:] @ W_head + b_head, then softmax ====
    transf32_kernel<<<dim3(32, 24), 256, 0, stream>>>(W_head, W_headT, D_, OUT_);
    head_kernel<<<(N_ * OUT_) / 4, 256, 0, stream>>>(x, W_headT, b_head, logits);
    softmax_out_kernel<<<N_, 256, 0, stream>>>(logits, (float*)d_out);
}